// Round 2
// baseline (552.460 us; speedup 1.0000x reference)
//
#include <hip/hip_runtime.h>

#define N_NODES 50000
#define N_EDGES 800000

typedef __attribute__((ext_vector_type(8))) short bf16x8;
typedef __attribute__((ext_vector_type(4))) float f32x4;

__device__ inline unsigned short f2bf(float f) {
  unsigned int u = __float_as_uint(f);
  unsigned int r = u + 0x7FFFu + ((u >> 16) & 1u);
  return (unsigned short)(r >> 16);
}

// ---------------- edge-index handling ----------------
// If edge_index is int64, every odd int32 word (high half, values < 2^31) is 0.
__global__ void detect_i64(const int* __restrict__ ei, int* __restrict__ flag) {
  int t = threadIdx.x;                 // 64 threads
  int v = ei[2 * t + 1];
  unsigned long long b = __ballot(v == 0);
  if (t == 0) *flag = (b == 0xFFFFFFFFFFFFFFFFull) ? 1 : 0;
}

__global__ void normalize_edges(const int* __restrict__ ei, int* __restrict__ src,
                                int* __restrict__ dst, const int* __restrict__ flag) {
  int e = blockIdx.x * 256 + threadIdx.x;
  if (e >= N_EDGES) return;
  if (*flag) { src[e] = ei[2 * e];       dst[e] = ei[2 * (N_EDGES + e)]; }
  else       { src[e] = ei[e];           dst[e] = ei[N_EDGES + e]; }
}

// ---------------- CSR build ----------------
__global__ void hist_k(const int* __restrict__ dst, int* __restrict__ cnt) {
  int e = blockIdx.x * 256 + threadIdx.x;
  if (e < N_EDGES) atomicAdd(&cnt[dst[e]], 1);
}

__device__ inline int block_excl_scan_256(int v, int& total) {
  __shared__ int lds[8];
  int lane = threadIdx.x & 63, wid = threadIdx.x >> 6;
  int orig = v;
#pragma unroll
  for (int off = 1; off < 64; off <<= 1) {
    int t = __shfl_up(v, off);
    if (lane >= off) v += t;
  }
  if (lane == 63) lds[wid] = v;
  __syncthreads();
  if (threadIdx.x == 0) {
    int s = 0;
    for (int w = 0; w < 4; ++w) { int t = lds[w]; lds[w] = s; s += t; }
    lds[4] = s;
  }
  __syncthreads();
  total = lds[4];
  return v + lds[wid] - orig;   // exclusive
}

__global__ __launch_bounds__(256) void scan1(const int* __restrict__ cnt,
                                             int* __restrict__ excl,
                                             int* __restrict__ partials) {
  int i = blockIdx.x * 256 + threadIdx.x;
  int v = (i < N_NODES) ? cnt[i] : 0;
  int total;
  int e = block_excl_scan_256(v, total);
  if (i < N_NODES) excl[i] = e;
  if (threadIdx.x == 0) partials[blockIdx.x] = total;
}

__global__ __launch_bounds__(256) void scan2(int* __restrict__ partials, int nb) {
  int i = threadIdx.x;
  int v = (i < nb) ? partials[i] : 0;
  int total;
  int e = block_excl_scan_256(v, total);
  if (i < nb) partials[i] = e;
}

__global__ __launch_bounds__(256) void scan3(int* __restrict__ row_ptr,
                                             const int* __restrict__ partials,
                                             int* __restrict__ cursor) {
  int i = blockIdx.x * 256 + threadIdx.x;
  if (i < N_NODES) {
    int v = row_ptr[i] + partials[blockIdx.x];
    row_ptr[i] = v;
    cursor[i] = v;
  }
  if (i == 0) row_ptr[N_NODES] = N_EDGES;
}

__global__ void scatter_k(const int* __restrict__ src, const int* __restrict__ dst,
                          int* __restrict__ cursor, int* __restrict__ ssrc) {
  int e = blockIdx.x * 256 + threadIdx.x;
  if (e < N_EDGES) {
    int p = atomicAdd(&cursor[dst[e]], 1);
    ssrc[p] = src[e];
  }
}

// ---------------- conversions / weight prep ----------------
__global__ void f32_to_bf16_vec(const float* __restrict__ in, unsigned short* __restrict__ out) {
  int i = blockIdx.x * 256 + threadIdx.x;  // exactly n/4 threads
  float4 v = ((const float4*)in)[i];
  ushort4 o;
  o.x = f2bf(v.x); o.y = f2bf(v.y); o.z = f2bf(v.z); o.w = f2bf(v.w);
  ((ushort4*)out)[i] = o;
}

// Build Bt[512][128] bf16, Bt[col][k] = W_sel[k][col&127], plus bias concat.
__global__ void prep_w(const float* __restrict__ Wq, const float* __restrict__ bq,
                       const float* __restrict__ Wk, const float* __restrict__ bk,
                       const float* __restrict__ Wv, const float* __restrict__ bv,
                       const float* __restrict__ Ws, const float* __restrict__ bs,
                       unsigned short* __restrict__ bt, float* __restrict__ bcat) {
  int t = blockIdx.x * 256 + threadIdx.x;  // 65536 threads
  int col = t >> 7, kk = t & 127;
  int sel = col >> 7, c = col & 127;
  const float* W = (sel == 0) ? Wq : (sel == 1) ? Wk : (sel == 2) ? Wv : Ws;
  bt[col * 128 + kk] = f2bf(W[kk * 128 + c]);
  if (kk == 0) {
    const float* B = (sel == 0) ? bq : (sel == 1) ? bk : (sel == 2) ? bv : bs;
    bcat[col] = B[c];
  }
}

// ---------------- GEMM: [50000x128]bf16 @ [128x512]bf16 -> O[50000][512]f32 ----------------
// wave job: 16-row tile x 64-col group, K=128. 5 row tiles per wave.
__global__ __launch_bounds__(256) void gemm_qkvs(const unsigned short* __restrict__ xb,
                                                 const unsigned short* __restrict__ bt,
                                                 const float* __restrict__ bias,
                                                 float* __restrict__ O) {
  const int wid = threadIdx.x >> 6;
  const int lane = threadIdx.x & 63;
  const int gw = blockIdx.x * 4 + wid;       // 0..4999
  const int colGroup = gw & 7;               // 8 col groups of 64
  const int rowGroup = gw >> 3;              // 0..624 (x5 row tiles)
  const int col0 = colGroup * 64;
  const int r = lane & 15;
  const int half = lane >> 4;                // 0..3

  bf16x8 bfrag[4][4];                        // [ct][kc]
#pragma unroll
  for (int ct = 0; ct < 4; ++ct) {
    int col = col0 + ct * 16 + r;
    const unsigned short* bp = bt + col * 128 + half * 8;
#pragma unroll
    for (int kc = 0; kc < 4; ++kc)
      bfrag[ct][kc] = *(const bf16x8*)(bp + kc * 32);
  }

#pragma unroll 1
  for (int rt = 0; rt < 5; ++rt) {
    int m0 = (rowGroup * 5 + rt) * 16;
    const unsigned short* ap = xb + (size_t)(m0 + r) * 128 + half * 8;
    bf16x8 afrag[4];
#pragma unroll
    for (int kc = 0; kc < 4; ++kc) afrag[kc] = *(const bf16x8*)(ap + kc * 32);
    f32x4 acc[4] = {{0.f,0.f,0.f,0.f},{0.f,0.f,0.f,0.f},{0.f,0.f,0.f,0.f},{0.f,0.f,0.f,0.f}};
#pragma unroll
    for (int ct = 0; ct < 4; ++ct)
#pragma unroll
      for (int kc = 0; kc < 4; ++kc)
        acc[ct] = __builtin_amdgcn_mfma_f32_16x16x32_bf16(afrag[kc], bfrag[ct][kc], acc[ct], 0, 0, 0);

    int orow = m0 + half * 4;
#pragma unroll
    for (int ct = 0; ct < 4; ++ct) {
      int col = col0 + ct * 16 + r;
      float bv = bias[col];
#pragma unroll
      for (int j = 0; j < 4; ++j)
        O[(size_t)(orow + j) * 512 + col] = acc[ct][j] + bv;
    }
  }
}

// ---------------- edge attention: one wave per destination node ----------------
// O row layout per node: [q(0:128) | k(128:256) | v(256:384) | s(384:512)]
template <int H, bool RELU>
__global__ __launch_bounds__(256) void edge_attn(const float* __restrict__ O,
                                                 const int* __restrict__ row_ptr,
                                                 const int* __restrict__ ssrc,
                                                 float* __restrict__ out,
                                                 float scale) {
  int wid = threadIdx.x >> 6, lane = threadIdx.x & 63;
  int n = blockIdx.x * 4 + wid;
  if (n >= N_NODES) return;
  const float2 q2 = *(const float2*)(O + (size_t)n * 512 + 2 * lane);
  float qx = q2.x * scale, qy = q2.y * scale;
  int start = row_ptr[n], end = row_ptr[n + 1];
  float acc0 = 0.f, acc1 = 0.f, den = 0.f;
  for (int idx = start; idx < end; ++idx) {
    int s = ssrc[idx];
    const float* base = O + (size_t)s * 512;
    float2 kk = *(const float2*)(base + 128 + 2 * lane);
    float2 vv = *(const float2*)(base + 256 + 2 * lane);
    float p = qx * kk.x + qy * kk.y;
#pragma unroll
    for (int off = 1; off < 64 / H; off <<= 1) p += __shfl_xor(p, off);
    float e = __expf(p);
    den += e;
    acc0 += e * vv.x;
    acc1 += e * vv.y;
  }
  float inv = 1.0f / (den + 1e-16f);
  float2 sk = *(const float2*)(O + (size_t)n * 512 + 384 + 2 * lane);
  float r0 = acc0 * inv + sk.x;
  float r1 = acc1 * inv + sk.y;
  if (RELU) { r0 = fmaxf(r0, 0.f); r1 = fmaxf(r1, 0.f); }
  *(float2*)(out + (size_t)n * 128 + 2 * lane) = make_float2(r0, r1);
}

// ---------------- launch ----------------
extern "C" void kernel_launch(void* const* d_in, const int* in_sizes, int n_in,
                              void* d_out, int out_size, void* d_ws, size_t ws_size,
                              hipStream_t stream) {
  (void)in_sizes; (void)n_in; (void)out_size; (void)ws_size;
  const float* x  = (const float*)d_in[0];
  const int*   ei = (const int*)d_in[1];
  const float *Wq1 = (const float*)d_in[2],  *bq1 = (const float*)d_in[3];
  const float *Wk1 = (const float*)d_in[4],  *bk1 = (const float*)d_in[5];
  const float *Wv1 = (const float*)d_in[6],  *bv1 = (const float*)d_in[7];
  const float *Ws1 = (const float*)d_in[8],  *bs1 = (const float*)d_in[9];
  const float *Wq2 = (const float*)d_in[10], *bq2 = (const float*)d_in[11];
  const float *Wk2 = (const float*)d_in[12], *bk2 = (const float*)d_in[13];
  const float *Wv2 = (const float*)d_in[14], *bv2 = (const float*)d_in[15];
  const float *Ws2 = (const float*)d_in[16], *bs2 = (const float*)d_in[17];
  float* out = (float*)d_out;

  char* w = (char*)d_ws;
  size_t off = 0;
  auto alloc = [&](size_t b) { void* p = w + off; off += (b + 255) & ~(size_t)255; return p; };
  int* flag   = (int*)alloc(4);
  int* src    = (int*)alloc((size_t)N_EDGES * 4);
  int* dstA   = (int*)alloc((size_t)N_EDGES * 4);
  int* ssrc   = (int*)alloc((size_t)N_EDGES * 4);
  int* rowp   = (int*)alloc((size_t)(N_NODES + 1) * 4);
  int* cursor = (int*)alloc((size_t)N_NODES * 4);
  int* cnt    = (int*)alloc((size_t)N_NODES * 4);
  int* part   = (int*)alloc(256 * 4);
  unsigned short* xb = (unsigned short*)alloc((size_t)N_NODES * 128 * 2);
  unsigned short* bt = (unsigned short*)alloc((size_t)512 * 128 * 2);
  float* bcat = (float*)alloc(512 * 4);
  float* O    = (float*)alloc((size_t)N_NODES * 512 * 4);
  float* h    = (float*)alloc((size_t)N_NODES * 128 * 4);

  hipMemsetAsync(cnt, 0, (size_t)N_NODES * 4, stream);
  detect_i64<<<1, 64, 0, stream>>>(ei, flag);
  normalize_edges<<<3125, 256, 0, stream>>>(ei, src, dstA, flag);
  hist_k<<<3125, 256, 0, stream>>>(dstA, cnt);
  scan1<<<196, 256, 0, stream>>>(cnt, rowp, part);
  scan2<<<1, 256, 0, stream>>>(part, 196);
  scan3<<<196, 256, 0, stream>>>(rowp, part, cursor);
  scatter_k<<<3125, 256, 0, stream>>>(src, dstA, cursor, ssrc);

  // ---- layer 1 (H=4, d=32) ----
  f32_to_bf16_vec<<<6250, 256, 0, stream>>>(x, xb);
  prep_w<<<256, 256, 0, stream>>>(Wq1, bq1, Wk1, bk1, Wv1, bv1, Ws1, bs1, bt, bcat);
  gemm_qkvs<<<1250, 256, 0, stream>>>(xb, bt, bcat, O);
  edge_attn<4, true><<<12500, 256, 0, stream>>>(O, rowp, ssrc, h, 0.17677669529663689f);

  // ---- layer 2 (H=1, d=128) ----
  f32_to_bf16_vec<<<6250, 256, 0, stream>>>(h, xb);
  prep_w<<<256, 256, 0, stream>>>(Wq2, bq2, Wk2, bk2, Wv2, bv2, Ws2, bs2, bt, bcat);
  gemm_qkvs<<<1250, 256, 0, stream>>>(xb, bt, bcat, O);
  edge_attn<1, false><<<12500, 256, 0, stream>>>(O, rowp, ssrc, out, 0.08838834764831845f);
}

// Round 3
// 436.159 us; speedup vs baseline: 1.2666x; 1.2666x over previous
//
#include <hip/hip_runtime.h>

#define N_NODES 50000
#define N_EDGES 800000

typedef __attribute__((ext_vector_type(8))) short bf16x8;
typedef __attribute__((ext_vector_type(4))) float f32x4;

__device__ inline unsigned short f2bf(float f) {
  unsigned int u = __float_as_uint(f);
  unsigned int r = u + 0x7FFFu + ((u >> 16) & 1u);
  return (unsigned short)(r >> 16);
}

// ---------------- edge-index handling ----------------
// If edge_index is int64, every odd int32 word (high half, values < 2^31) is 0.
__global__ void detect_i64(const int* __restrict__ ei, int* __restrict__ flag) {
  int t = threadIdx.x;                 // 64 threads
  int v = ei[2 * t + 1];
  unsigned long long b = __ballot(v == 0);
  if (t == 0) *flag = (b == 0xFFFFFFFFFFFFFFFFull) ? 1 : 0;
}

// fused: normalize edge dtype + write src/dst + histogram of dst
__global__ void edges_prep(const int* __restrict__ ei, const int* __restrict__ flag,
                           int* __restrict__ src, int* __restrict__ dst,
                           int* __restrict__ cnt) {
  int e = blockIdx.x * 256 + threadIdx.x;
  if (e >= N_EDGES) return;
  int s, d;
  if (*flag) { s = ei[2 * e]; d = ei[2 * (N_EDGES + e)]; }
  else       { s = ei[e];     d = ei[N_EDGES + e]; }
  src[e] = s; dst[e] = d;
  atomicAdd(&cnt[d], 1);
}

// ---------------- CSR build ----------------
__device__ inline int block_excl_scan_256(int v, int& total) {
  __shared__ int lds[8];
  int lane = threadIdx.x & 63, wid = threadIdx.x >> 6;
  int orig = v;
#pragma unroll
  for (int off = 1; off < 64; off <<= 1) {
    int t = __shfl_up(v, off);
    if (lane >= off) v += t;
  }
  if (lane == 63) lds[wid] = v;
  __syncthreads();
  if (threadIdx.x == 0) {
    int s = 0;
    for (int w = 0; w < 4; ++w) { int t = lds[w]; lds[w] = s; s += t; }
    lds[4] = s;
  }
  __syncthreads();
  total = lds[4];
  return v + lds[wid] - orig;   // exclusive
}

__global__ __launch_bounds__(256) void scan1(const int* __restrict__ cnt,
                                             int* __restrict__ excl,
                                             int* __restrict__ partials) {
  int i = blockIdx.x * 256 + threadIdx.x;
  int v = (i < N_NODES) ? cnt[i] : 0;
  int total;
  int e = block_excl_scan_256(v, total);
  if (i < N_NODES) excl[i] = e;
  if (threadIdx.x == 0) partials[blockIdx.x] = total;
}

__global__ __launch_bounds__(256) void scan2(int* __restrict__ partials, int nb) {
  int i = threadIdx.x;
  int v = (i < nb) ? partials[i] : 0;
  int total;
  int e = block_excl_scan_256(v, total);
  if (i < nb) partials[i] = e;
}

__global__ __launch_bounds__(256) void scan3(int* __restrict__ row_ptr,
                                             const int* __restrict__ partials,
                                             int* __restrict__ cursor) {
  int i = blockIdx.x * 256 + threadIdx.x;
  if (i < N_NODES) {
    int v = row_ptr[i] + partials[blockIdx.x];
    row_ptr[i] = v;
    cursor[i] = v;
  }
  if (i == 0) row_ptr[N_NODES] = N_EDGES;
}

__global__ void scatter_k(const int* __restrict__ src, const int* __restrict__ dst,
                          int* __restrict__ cursor, int* __restrict__ ssrc) {
  int e = blockIdx.x * 256 + threadIdx.x;
  if (e < N_EDGES) {
    int p = atomicAdd(&cursor[dst[e]], 1);
    ssrc[p] = src[e];
  }
}

// ---------------- conversions / weight prep ----------------
__global__ void f32_to_bf16_vec(const float* __restrict__ in, unsigned short* __restrict__ out) {
  int i = blockIdx.x * 256 + threadIdx.x;  // exactly n/4 threads
  float4 v = ((const float4*)in)[i];
  ushort4 o;
  o.x = f2bf(v.x); o.y = f2bf(v.y); o.z = f2bf(v.z); o.w = f2bf(v.w);
  ((ushort4*)out)[i] = o;
}

// Build Bt[512][128] bf16, Bt[col][k] = W_sel[k][col&127], plus bias concat.
__global__ void prep_w(const float* __restrict__ Wq, const float* __restrict__ bq,
                       const float* __restrict__ Wk, const float* __restrict__ bk,
                       const float* __restrict__ Wv, const float* __restrict__ bv,
                       const float* __restrict__ Ws, const float* __restrict__ bs,
                       unsigned short* __restrict__ bt, float* __restrict__ bcat) {
  int t = blockIdx.x * 256 + threadIdx.x;  // 65536 threads
  int col = t >> 7, kk = t & 127;
  int sel = col >> 7, c = col & 127;
  const float* W = (sel == 0) ? Wq : (sel == 1) ? Wk : (sel == 2) ? Wv : Ws;
  bt[col * 128 + kk] = f2bf(W[kk * 128 + c]);
  if (kk == 0) {
    const float* B = (sel == 0) ? bq : (sel == 1) ? bk : (sel == 2) ? bv : bs;
    bcat[col] = B[c];
  }
}

// ---------------- GEMM: [50000x128]bf16 @ [128x512]bf16 ----------------
// Output split: q (cols 0..127) -> Oq f32 [N][128]
//               k (128..255), v (256..383) -> Okv bf16 [N][256] interleaved:
//                   entry 4t+0=k(2t) 4t+1=k(2t+1) 4t+2=v(2t) 4t+3=v(2t+1)
//               s (384..511) -> Os f32 [N][128]
__global__ __launch_bounds__(256) void gemm_qkvs(const unsigned short* __restrict__ xb,
                                                 const unsigned short* __restrict__ bt,
                                                 const float* __restrict__ bias,
                                                 float* __restrict__ Oq,
                                                 unsigned short* __restrict__ Okv,
                                                 float* __restrict__ Os) {
  const int wid = threadIdx.x >> 6;
  const int lane = threadIdx.x & 63;
  const int gw = blockIdx.x * 4 + wid;       // 0..4999
  const int colGroup = gw & 7;               // 8 col groups of 64
  const int rowGroup = gw >> 3;              // 0..624 (x5 row tiles)
  const int col0 = colGroup * 64;
  const int r = lane & 15;
  const int half = lane >> 4;                // 0..3

  bf16x8 bfrag[4][4];                        // [ct][kc]
#pragma unroll
  for (int ct = 0; ct < 4; ++ct) {
    int col = col0 + ct * 16 + r;
    const unsigned short* bp = bt + col * 128 + half * 8;
#pragma unroll
    for (int kc = 0; kc < 4; ++kc)
      bfrag[ct][kc] = *(const bf16x8*)(bp + kc * 32);
  }

#pragma unroll 1
  for (int rt = 0; rt < 5; ++rt) {
    int m0 = (rowGroup * 5 + rt) * 16;
    const unsigned short* ap = xb + (size_t)(m0 + r) * 128 + half * 8;
    bf16x8 afrag[4];
#pragma unroll
    for (int kc = 0; kc < 4; ++kc) afrag[kc] = *(const bf16x8*)(ap + kc * 32);
    f32x4 acc[4] = {{0.f,0.f,0.f,0.f},{0.f,0.f,0.f,0.f},{0.f,0.f,0.f,0.f},{0.f,0.f,0.f,0.f}};
#pragma unroll
    for (int ct = 0; ct < 4; ++ct)
#pragma unroll
      for (int kc = 0; kc < 4; ++kc)
        acc[ct] = __builtin_amdgcn_mfma_f32_16x16x32_bf16(afrag[kc], bfrag[ct][kc], acc[ct], 0, 0, 0);

    int orow = m0 + half * 4;
    if (colGroup < 2) {            // q -> f32
#pragma unroll
      for (int ct = 0; ct < 4; ++ct) {
        int col = col0 + ct * 16 + r;
        float bv = bias[col];
#pragma unroll
        for (int j = 0; j < 4; ++j)
          Oq[(size_t)(orow + j) * 128 + col] = acc[ct][j] + bv;
      }
    } else if (colGroup >= 6) {    // s -> f32
#pragma unroll
      for (int ct = 0; ct < 4; ++ct) {
        int col = col0 + ct * 16 + r;
        float bv = bias[col];
        int c = col - 384;
#pragma unroll
        for (int j = 0; j < 4; ++j)
          Os[(size_t)(orow + j) * 128 + c] = acc[ct][j] + bv;
      }
    } else {                       // k or v -> bf16 interleaved
      const int voff  = (colGroup >= 4) ? 2 : 0;
      const int cbase = (colGroup >= 4) ? 256 : 128;
#pragma unroll
      for (int ct = 0; ct < 4; ++ct) {
        int col = col0 + ct * 16 + r;
        float bv = bias[col];
        int c = col - cbase;
        int pos = ((c >> 1) << 2) + voff + (c & 1);
#pragma unroll
        for (int j = 0; j < 4; ++j)
          Okv[(size_t)(orow + j) * 256 + pos] = f2bf(acc[ct][j] + bv);
      }
    }
  }
}

// ---------------- edge attention: one wave per destination node ----------------
// Lane l owns channels 2l, 2l+1. Gather: one uint2 (8B) per lane per edge.
template <int H, bool OUTBF>
__global__ __launch_bounds__(256) void edge_attn(const float* __restrict__ Oq,
                                                 const unsigned short* __restrict__ Okv,
                                                 const float* __restrict__ Os,
                                                 const int* __restrict__ row_ptr,
                                                 const int* __restrict__ ssrc,
                                                 void* __restrict__ outp,
                                                 float scale) {
  int wid = threadIdx.x >> 6, lane = threadIdx.x & 63;
  int n = blockIdx.x * 4 + wid;
  if (n >= N_NODES) return;
  const float2 q2 = *(const float2*)(Oq + (size_t)n * 128 + 2 * lane);
  float qx = q2.x * scale, qy = q2.y * scale;
  int start = row_ptr[n], end = row_ptr[n + 1];
  int len = end - start;
  const int* sp = ssrc + start;
  const uint2* kvb = (const uint2*)Okv;  // node stride: 64 uint2
  float acc0 = 0.f, acc1 = 0.f, den = 0.f;

  auto proc = [&](uint2 kv) {
    float k0 = __uint_as_float(kv.x << 16);
    float k1 = __uint_as_float(kv.x & 0xffff0000u);
    float p = qx * k0 + qy * k1;
#pragma unroll
    for (int off = 1; off < 64 / H; off <<= 1) p += __shfl_xor(p, off);
    float e = __expf(p);
    float v0 = __uint_as_float(kv.y << 16);
    float v1 = __uint_as_float(kv.y & 0xffff0000u);
    den += e; acc0 += e * v0; acc1 += e * v1;
  };

  if (len >= 2) {
    int sA = sp[0], sB = sp[1];
    uint2 kvA = kvb[(size_t)sA * 64 + lane];
    uint2 kvB = kvb[(size_t)sB * 64 + lane];
    for (int i = 2; i < len; ++i) {
      int sN = sp[i];
      uint2 kvN = kvb[(size_t)sN * 64 + lane];
      proc(kvA);
      kvA = kvB; kvB = kvN;
    }
    proc(kvA); proc(kvB);
  } else if (len == 1) {
    proc(kvb[(size_t)sp[0] * 64 + lane]);
  }

  float inv = 1.0f / (den + 1e-16f);
  float2 sk = *(const float2*)(Os + (size_t)n * 128 + 2 * lane);
  float r0 = acc0 * inv + sk.x;
  float r1 = acc1 * inv + sk.y;
  if (OUTBF) {  // layer 1: relu + pack bf16 directly into xb for layer-2 GEMM
    r0 = fmaxf(r0, 0.f); r1 = fmaxf(r1, 0.f);
    unsigned int pk = (unsigned int)f2bf(r0) | ((unsigned int)f2bf(r1) << 16);
    ((unsigned int*)outp)[(size_t)n * 64 + lane] = pk;
  } else {
    ((float2*)outp)[(size_t)n * 64 + lane] = make_float2(r0, r1);
  }
}

// ---------------- launch ----------------
extern "C" void kernel_launch(void* const* d_in, const int* in_sizes, int n_in,
                              void* d_out, int out_size, void* d_ws, size_t ws_size,
                              hipStream_t stream) {
  (void)in_sizes; (void)n_in; (void)out_size; (void)ws_size;
  const float* x  = (const float*)d_in[0];
  const int*   ei = (const int*)d_in[1];
  const float *Wq1 = (const float*)d_in[2],  *bq1 = (const float*)d_in[3];
  const float *Wk1 = (const float*)d_in[4],  *bk1 = (const float*)d_in[5];
  const float *Wv1 = (const float*)d_in[6],  *bv1 = (const float*)d_in[7];
  const float *Ws1 = (const float*)d_in[8],  *bs1 = (const float*)d_in[9];
  const float *Wq2 = (const float*)d_in[10], *bq2 = (const float*)d_in[11];
  const float *Wk2 = (const float*)d_in[12], *bk2 = (const float*)d_in[13];
  const float *Wv2 = (const float*)d_in[14], *bv2 = (const float*)d_in[15];
  const float *Ws2 = (const float*)d_in[16], *bs2 = (const float*)d_in[17];
  float* out = (float*)d_out;

  char* w = (char*)d_ws;
  size_t off = 0;
  auto alloc = [&](size_t b) { void* p = w + off; off += (b + 255) & ~(size_t)255; return p; };
  int* flag   = (int*)alloc(4);
  int* src    = (int*)alloc((size_t)N_EDGES * 4);
  int* dstA   = (int*)alloc((size_t)N_EDGES * 4);
  int* ssrc   = (int*)alloc((size_t)N_EDGES * 4);
  int* rowp   = (int*)alloc((size_t)(N_NODES + 1) * 4);
  int* cursor = (int*)alloc((size_t)N_NODES * 4);
  int* cnt    = (int*)alloc((size_t)N_NODES * 4);
  int* part   = (int*)alloc(256 * 4);
  unsigned short* xb = (unsigned short*)alloc((size_t)N_NODES * 128 * 2);
  unsigned short* bt = (unsigned short*)alloc((size_t)512 * 128 * 2);
  float* bcat = (float*)alloc(512 * 4);
  float* Oq   = (float*)alloc((size_t)N_NODES * 128 * 4);
  unsigned short* Okv = (unsigned short*)alloc((size_t)N_NODES * 256 * 2);
  float* Os   = (float*)alloc((size_t)N_NODES * 128 * 4);

  hipMemsetAsync(cnt, 0, (size_t)N_NODES * 4, stream);
  detect_i64<<<1, 64, 0, stream>>>(ei, flag);
  edges_prep<<<3125, 256, 0, stream>>>(ei, flag, src, dstA, cnt);
  scan1<<<196, 256, 0, stream>>>(cnt, rowp, part);
  scan2<<<1, 256, 0, stream>>>(part, 196);
  scan3<<<196, 256, 0, stream>>>(rowp, part, cursor);
  scatter_k<<<3125, 256, 0, stream>>>(src, dstA, cursor, ssrc);

  // ---- layer 1 (H=4, d=32) ----
  f32_to_bf16_vec<<<6250, 256, 0, stream>>>(x, xb);
  prep_w<<<256, 256, 0, stream>>>(Wq1, bq1, Wk1, bk1, Wv1, bv1, Ws1, bs1, bt, bcat);
  gemm_qkvs<<<1250, 256, 0, stream>>>(xb, bt, bcat, Oq, Okv, Os);
  edge_attn<4, true><<<12500, 256, 0, stream>>>(Oq, Okv, Os, rowp, ssrc, xb, 0.17677669529663689f);

  // ---- layer 2 (H=1, d=128) ----
  prep_w<<<256, 256, 0, stream>>>(Wq2, bq2, Wk2, bk2, Wv2, bv2, Ws2, bs2, bt, bcat);
  gemm_qkvs<<<1250, 256, 0, stream>>>(xb, bt, bcat, Oq, Okv, Os);
  edge_attn<1, false><<<12500, 256, 0, stream>>>(Oq, Okv, Os, rowp, ssrc, out, 0.08838834764831845f);
}